// Round 6
// baseline (247.236 us; speedup 1.0000x reference)
//
#include <hip/hip_runtime.h>
#include <hip/hip_bf16.h>

typedef float f32x4 __attribute__((ext_vector_type(4)));
typedef short bf16x8 __attribute__((ext_vector_type(8)));
typedef short bf16x4 __attribute__((ext_vector_type(4)));

static __device__ __forceinline__ short f2bs(float f) {
  __hip_bfloat16 h = __float2bfloat16(f);
  union { __hip_bfloat16 h; short s; } u;
  u.h = h;
  return u.s;
}

// async global->LDS, 16B per lane; LDS dest = wave-uniform base + lane*16
#define GLDS(gp, lp) __builtin_amdgcn_global_load_lds( \
    (const __attribute__((address_space(1))) unsigned int*)(gp), \
    (__attribute__((address_space(3))) unsigned int*)(lp), 16, 0, 0)

// ---------------- fused preprocessing: one launch instead of three ----------
// blocks [0,8192): f32->bf16 of x (flat).
// blocks [8192,11264): transpose+cvt w_qkv [1024][3072] -> [3072][1024]
// blocks [11264,12288): transpose+cvt w_o [1024][1024] -> [1024][1024]
// Launch overhead ~10us/kernel; 6->4 launches saves ~20us total.
__global__ __launch_bounds__(256) void prep(const float* __restrict__ x,
                                            const float* __restrict__ w_qkv,
                                            const float* __restrict__ w_o,
                                            short* __restrict__ xb,
                                            short* __restrict__ wqkvT,
                                            short* __restrict__ woT) {
  __shared__ float tile[32][33];
  const int bid = blockIdx.x;
  if (bid < 8192) {
    int i = bid * 256 + threadIdx.x;
    f32x4 v = ((const f32x4*)x)[i];
    bf16x4 o;
    o[0] = f2bs(v[0]); o[1] = f2bs(v[1]); o[2] = f2bs(v[2]); o[3] = f2bs(v[3]);
    ((bf16x4*)xb)[i] = o;
    return;
  }
  const float* in; short* out; int R, C, bx, by;
  if (bid < 11264) {
    int b2 = bid - 8192;                 // 3072 blocks = 96 x 32
    in = w_qkv; out = wqkvT; R = 1024; C = 3072;
    bx = (b2 % 96) * 32; by = (b2 / 96) * 32;
  } else {
    int b3 = bid - 11264;                // 1024 blocks = 32 x 32
    in = w_o; out = woT; R = 1024; C = 1024;
    bx = (b3 % 32) * 32; by = (b3 / 32) * 32;
  }
  const int tx = threadIdx.x & 31;
  const int ty = threadIdx.x >> 5;
#pragma unroll
  for (int i = 0; i < 32; i += 8)
    tile[ty + i][tx] = in[(long)(by + ty + i) * C + bx + tx];
  __syncthreads();
#pragma unroll
  for (int i = 0; i < 32; i += 8)
    out[(long)(bx + ty + i) * R + by + tx] = f2bs(tile[tx][ty + i]);
}

// ======== proven structure: A+B staged via GLDS, double-buffered,
// one barrier per K-tile (prefetch next buffer right after barrier). ========
// Round-6 LDS swizzle (rule 21: both-sides-or-neither with global_load_lds):
// row stride is 64B -> lanes with equal quad and equal lr&1 (8 lanes) hit the
// same 4-bank group with different rows = 8-way conflict (2.94x, m136).
// Fix: LDS dest stays linear; the global SOURCE column block is pre-swizzled
// j ^= (row>>1)&3 (row = 16m + lane>>2 -> key = (lane>>3)&3), and the
// ds_read applies the same XOR (key = (lr>>1)&3). Conflict set spreads over
// 4 bank groups x 2 lanes (2-way = free). Predicted: SQ_LDS_BANK_CONFLICT
// 6.29M -> <1M per gemm_qkv dispatch.
__device__ __forceinline__ void gemm_compute_tile(const short* Ac, const short* Bc,
                                                  int r0, int c0, int lr, int quad,
                                                  f32x4 acc[4][4]) {
  const int rq = (quad ^ ((lr >> 1) & 3)) * 8;   // swizzled 16B-block offset
  bf16x8 af[4], bfr[4];
#pragma unroll
  for (int i = 0; i < 4; ++i)
    af[i] = *(const bf16x8*)(Ac + (r0 + i * 16 + lr) * 32 + rq);
#pragma unroll
  for (int j = 0; j < 4; ++j)
    bfr[j] = *(const bf16x8*)(Bc + (c0 + j * 16 + lr) * 32 + rq);
#pragma unroll
  for (int i = 0; i < 4; ++i)
#pragma unroll
    for (int j = 0; j < 4; ++j)
      acc[i][j] = __builtin_amdgcn_mfma_f32_16x16x32_bf16(af[i], bfr[j], acc[i][j], 0, 0, 0);
}

// 256-thread / 128x128-tile mainloop (used by BOTH gemm_qkv and gemm_out).
// 32 KB LDS -> 4-5 blocks/CU resource-limited; VGPR ~48 + 64 AGPR fits.
// NOTE round-2 lesson: do NOT force waves/EU via launch_bounds above 5 —
// RA spills the 64-reg accumulator (VGPR 56->40, 1.7 GB scratch traffic,
// 4.4x slowdown). Residency must come from geometry, not hints.
__device__ __forceinline__ void gemm_mainloop(const short* __restrict__ A,
                                              const short* __restrict__ Bt,
                                              int K, int rowA0, int rowB0,
                                              short* As, short* Bs,  // each 2*128*32
                                              f32x4 acc[4][4]) {
  const int tid = threadIdx.x;
  const int wave = tid >> 6;
  const int lane = tid & 63;
  const int lr = lane & 15;
  const int quad = lane >> 4;
  // pre-swizzled source column block (see gemm_compute_tile comment)
  const int swz = ((lane & 3) ^ ((lane >> 3) & 3)) * 8;
  const short* aP = A + (long)(rowA0 + wave * 32 + (lane >> 2)) * K + swz;
  const short* bP = Bt + (long)(rowB0 + wave * 32 + (lane >> 2)) * K + swz;
  const int woff = wave * 32 * 32;
  const int r0 = (wave >> 1) * 64;
  const int c0 = (wave & 1) * 64;
  const int c16K = 16 * K;
  const int BUF = 128 * 32;
  GLDS(aP, As + woff);
  GLDS(aP + c16K, As + woff + 16 * 32);
  GLDS(bP, Bs + woff);
  GLDS(bP + c16K, Bs + woff + 16 * 32);
  aP += 32; bP += 32;
  const int nIter = K >> 5;   // even
#pragma unroll 1
  for (int i = 0; i < nIter; i += 2) {
    __syncthreads();                       // buf0 ready
    if (i + 1 < nIter) {
      GLDS(aP, As + BUF + woff);
      GLDS(aP + c16K, As + BUF + woff + 16 * 32);
      GLDS(bP, Bs + BUF + woff);
      GLDS(bP + c16K, Bs + BUF + woff + 16 * 32);
      aP += 32; bP += 32;
    }
    gemm_compute_tile(As, Bs, r0, c0, lr, quad, acc);
    __syncthreads();                       // buf1 ready
    if (i + 2 < nIter) {
      GLDS(aP, As + woff);
      GLDS(aP + c16K, As + woff + 16 * 32);
      GLDS(bP, Bs + woff);
      GLDS(bP + c16K, Bs + woff + 16 * 32);
      aP += 32; bP += 32;
    }
    gemm_compute_tile(As + BUF, Bs + BUF, r0, c0, lr, quad, acc);
  }
}

// ---------------- GEMM1: qkv = x @ w_qkv ----------------
__global__ __launch_bounds__(256, 5) void gemm_qkv(const short* __restrict__ xb,
                                                   const short* __restrict__ wT,
                                                   short* __restrict__ q,
                                                   short* __restrict__ k,
                                                   short* __restrict__ vt) {
  __shared__ __align__(16) short As[2 * 128 * 32];
  __shared__ __align__(16) short Bs[2 * 128 * 32];
  f32x4 acc[4][4];
#pragma unroll
  for (int i = 0; i < 4; ++i)
#pragma unroll
    for (int j = 0; j < 4; ++j)
      acc[i][j] = (f32x4){0.f, 0.f, 0.f, 0.f};
  const int tileM = blockIdx.x * 128;
  const int tileN = blockIdx.y * 128;
  gemm_mainloop(xb, wT, 1024, tileM, tileN, As, Bs, acc);
  const int tid = threadIdx.x;
  const int wave = tid >> 6;
  const int lane = tid & 63;
  const int lr = lane & 15;
  const int quad = lane >> 4;
  const int wrow = wave >> 1;      // 0..1
  const int wcol = wave & 1;       // 0..1
  // epilogue: scatter into q/k/v^T
#pragma unroll
  for (int i = 0; i < 4; ++i) {
    const int row0 = tileM + wrow * 64 + i * 16 + quad * 4;  // 4 consecutive rows
    const int b = row0 >> 11;
    const int t = row0 & 2047;
#pragma unroll
    for (int j = 0; j < 4; ++j) {
      int col = tileN + wcol * 64 + j * 16 + lr;
      int region = col >> 10;    // 0=q 1=k 2=v (wave-uniform)
      int w = col & 1023;
      int h = w >> 6;
      int d = w & 63;
      long bh = (long)b * 16 + h;
      if (region == 0) {
#pragma unroll
        for (int r = 0; r < 4; ++r)
          q[(bh * 2048 + t + r) * 64 + d] = f2bs(acc[i][j][r] * 0.03125f);  // fold 1/sqrt(C)
      } else if (region == 1) {
#pragma unroll
        for (int r = 0; r < 4; ++r)
          k[(bh * 2048 + t + r) * 64 + d] = f2bs(acc[i][j][r]);
      } else {
        bf16x4 pk;  // 4 consecutive t -> one b64 store into vt[bh][d][t..t+3]
#pragma unroll
        for (int r = 0; r < 4; ++r) pk[r] = f2bs(acc[i][j][r]);
        *(bf16x4*)(vt + (bh * 64 + d) * 2048 + t) = pk;
      }
    }
  }
}

// ---------------- flash attention with ALiBi + causal ----------------
// 2048 blocks, one 64-row q-tile each, descending-j dispatch (LPT schedule).
// Fixed-max softmax (max=2.0): no online max/rescale; l reduced at epilogue.
// S^T orientation -> b64 packed P commits. Bias in registers; causal bitmask.
// h-mix remap (round 1): rotate bh by bit-reversed residency round so each
// CU's 8 resident blocks sample 8 different heads -> per-CU work ~= mean.
// Round-4/5 lesson: ones-MFMA l-sum caused WRITE_SIZE 29->150MB regression
// (never re-land); setprio alone is neutral-positive (kept).
__global__ __launch_bounds__(256, 5) void attn(const short* __restrict__ q,
                                               const short* __restrict__ kk,
                                               const short* __restrict__ vt,
                                               short* __restrict__ cat) {
  __shared__ __align__(16) short Ks[64 * 72];       // [kpos][dh], pad 72
  __shared__ __align__(16) short Vs[64 * 72];       // [d][kpos], pad 72
  __shared__ __align__(16) short Ps[4 * 16 * 72];   // per-wave P [m=16][k=64+pad]
  const int bx = blockIdx.x;                        // 0..2047
  const int g = bx >> 8;                            // residency round 0..7
  const int hshift = ((g & 1) << 3) | ((g & 2) << 1) | ((g & 4) >> 1);
  const int j = 31 - (bx >> 6);                     // q-tile index (64 rows)
  const int bh = (bx + hshift) & 63;                // h-mixed across CUs
  const int h = bh & 15;
  const int b = bh >> 4;
  const int tid = threadIdx.x;
  const int wave = tid >> 6;
  const int lane = tid & 63;
  const int lr = lane & 15;
  const int quad = lane >> 4;
  const float l2e = 1.44269504f;
  const float slope = exp2f(-0.5f * (float)(h + 1));   // 2^(-(h+1)/2)
  const float slope_l2e = slope * l2e;
  const float c2 = -2.0f * l2e;                        // fixed max = 2.0
  const int d_cut = (int)ceilf(20.0f * exp2f(0.5f * (float)(h + 1)));
  const short* kbg = kk + (long)bh * 2048 * 64;
  const short* vbg = vt + (long)bh * 64 * 2048;
  const int srow = tid >> 3;          // 0..31
  const int scol = (tid & 7) * 8;     // 0..56
  short* pw = Ps + wave * 16 * 72;

  const int q0 = j * 64;
  const int mrow0 = q0 + wave * 16;           // this wave's 16 q-rows (m = lr)
  const int kt_start = max(0, (q0 - d_cut) >> 6);
  const short* qptr = q + ((long)bh * 2048 + mrow0) * 64;
  bf16x8 qf0 = *(const bf16x8*)(qptr + (long)lr * 64 + quad * 8);
  bf16x8 qf1 = *(const bf16x8*)(qptr + (long)lr * 64 + 32 + quad * 8);
  float lp = 0.f;                             // per-lane partial row-sum (m=lr)
  f32x4 O[4];
#pragma unroll
  for (int dt = 0; dt < 4; ++dt) O[dt] = (f32x4){0.f, 0.f, 0.f, 0.f};
  // bias regs: bias[ct][r] = slope_l2e*(kbase + ct*16+quad*4+r - mrow0 - lr) + c2
  float bias[4][4];
  unsigned okbits = 0;                        // diag-tile causal mask (dist<=0)
#pragma unroll
  for (int ct = 0; ct < 4; ++ct)
#pragma unroll
    for (int r = 0; r < 4; ++r) {
      int off = ct * 16 + quad * 4 + r;
      bias[ct][r] = slope_l2e * (float)(kt_start * 64 + off - mrow0 - lr) + c2;
      if (off - wave * 16 - lr <= 0) okbits |= 1u << (ct * 4 + r);
    }
  const float bstep = slope_l2e * 64.0f;

  // prefetch first tile into registers
  const short* kg = kbg + (long)kt_start * 64 * 64;
  const short* vg = vbg + kt_start * 64;
  bf16x8 pk0 = *(const bf16x8*)(kg + srow * 64 + scol);
  bf16x8 pk1 = *(const bf16x8*)(kg + (srow + 32) * 64 + scol);
  bf16x8 pv0 = *(const bf16x8*)(vg + (long)srow * 2048 + scol);
  bf16x8 pv1 = *(const bf16x8*)(vg + (long)(srow + 32) * 2048 + scol);
  for (int kt = kt_start; kt <= j; ++kt) {
    *(bf16x8*)(Ks + srow * 72 + scol) = pk0;
    *(bf16x8*)(Ks + (srow + 32) * 72 + scol) = pk1;
    *(bf16x8*)(Vs + srow * 72 + scol) = pv0;
    *(bf16x8*)(Vs + (srow + 32) * 72 + scol) = pv1;
    __syncthreads();  // LDS tile ready
    if (kt < j) {     // issue next tile's loads; latency overlaps compute
      const short* kg2 = kbg + (long)(kt + 1) * 64 * 64;
      const short* vg2 = vbg + (kt + 1) * 64;
      pk0 = *(const bf16x8*)(kg2 + srow * 64 + scol);
      pk1 = *(const bf16x8*)(kg2 + (srow + 32) * 64 + scol);
      pv0 = *(const bf16x8*)(vg2 + (long)srow * 2048 + scol);
      pv1 = *(const bf16x8*)(vg2 + (long)(srow + 32) * 2048 + scol);
    }
    // S^T = K Q^T: lane holds S^T[k = kbase+ct*16+quad*4+r][m = mrow0+lr]
    f32x4 S[4];
    __builtin_amdgcn_s_setprio(1);
#pragma unroll
    for (int ct = 0; ct < 4; ++ct) {
      bf16x8 kf0 = *(const bf16x8*)(Ks + (ct * 16 + lr) * 72 + quad * 8);
      bf16x8 kf1 = *(const bf16x8*)(Ks + (ct * 16 + lr) * 72 + 32 + quad * 8);
      f32x4 a = (f32x4){0.f, 0.f, 0.f, 0.f};
      a = __builtin_amdgcn_mfma_f32_16x16x32_bf16(kf0, qf0, a, 0, 0, 0);
      a = __builtin_amdgcn_mfma_f32_16x16x32_bf16(kf1, qf1, a, 0, 0, 0);
      S[ct] = a;
    }
    __builtin_amdgcn_s_setprio(0);
    // fixed-max softmax: p = exp2(S*l2e + bias)
    const bool diag = (kt == j);
#pragma unroll
    for (int ct = 0; ct < 4; ++ct) {
      bf16x4 pkt;
#pragma unroll
      for (int r = 0; r < 4; ++r) {
        float arg = fmaf(S[ct][r], l2e, bias[ct][r]);
        if (diag && !(okbits & (1u << (ct * 4 + r)))) arg = -10000.0f;  // causal
        float p = exp2f(arg);
        lp += p;
        pkt[r] = f2bs(p);
        bias[ct][r] += bstep;
      }
      // 4 consecutive k -> one b64 write into P[m=lr][k]
      *(bf16x4*)(pw + lr * 72 + ct * 16 + quad * 4) = pkt;
    }
    asm volatile("s_waitcnt lgkmcnt(0)" ::: "memory");  // wave-private scratch
    bf16x8 pf0 = *(const bf16x8*)(pw + lr * 72 + quad * 8);
    bf16x8 pf1 = *(const bf16x8*)(pw + lr * 72 + 32 + quad * 8);
    __builtin_amdgcn_s_setprio(1);
#pragma unroll
    for (int dt = 0; dt < 4; ++dt) {
      bf16x8 vf0 = *(const bf16x8*)(Vs + (dt * 16 + lr) * 72 + quad * 8);
      bf16x8 vf1 = *(const bf16x8*)(Vs + (dt * 16 + lr) * 72 + 32 + quad * 8);
      O[dt] = __builtin_amdgcn_mfma_f32_16x16x32_bf16(pf0, vf0, O[dt], 0, 0, 0);
      O[dt] = __builtin_amdgcn_mfma_f32_16x16x32_bf16(pf1, vf1, O[dt], 0, 0, 0);
    }
    __builtin_amdgcn_s_setprio(0);
    __syncthreads();  // all waves done with Ks/Vs before next commit
  }
  // reduce l across the 4 quads (lane's partial covers k = {ct*16+quad*4+r})
  lp += __shfl_xor(lp, 16);
  lp += __shfl_xor(lp, 32);   // now every lane holds full l for row m = lr
  // epilogue: O rows are m = quad*4+r -> fetch l via shuffle
#pragma unroll
  for (int r = 0; r < 4; ++r) {
    float lm = __shfl(lp, quad * 4 + r);
    float inv = 1.0f / lm;
    int t = mrow0 + quad * 4 + r;
#pragma unroll
    for (int dt = 0; dt < 4; ++dt)
      cat[((long)b * 2048 + t) * 1024 + h * 64 + dt * 16 + lr] =
          f2bs(O[dt][r] * inv);
  }
}

// ---------------- GEMM2: out = concat @ w_o (fp32 out) ----------------
__global__ __launch_bounds__(256, 5) void gemm_out(const short* __restrict__ cat,
                                                   const short* __restrict__ woT,
                                                   float* __restrict__ out) {
  __shared__ __align__(16) short As[2 * 128 * 32];
  __shared__ __align__(16) short Bs[2 * 128 * 32];
  f32x4 acc[4][4];
#pragma unroll
  for (int i = 0; i < 4; ++i)
#pragma unroll
    for (int j = 0; j < 4; ++j)
      acc[i][j] = (f32x4){0.f, 0.f, 0.f, 0.f};
  const int tileM = blockIdx.x * 128;
  const int tileN = blockIdx.y * 128;
  gemm_mainloop(cat, woT, 1024, tileM, tileN, As, Bs, acc);
  const int tid = threadIdx.x;
  const int wave = tid >> 6;
  const int lane = tid & 63;
  const int lr = lane & 15;
  const int quad = lane >> 4;
#pragma unroll
  for (int i = 0; i < 4; ++i)
#pragma unroll
    for (int j = 0; j < 4; ++j) {
      int col = tileN + (wave & 1) * 64 + j * 16 + lr;
#pragma unroll
      for (int r = 0; r < 4; ++r) {
        int row = tileM + (wave >> 1) * 64 + i * 16 + quad * 4 + r;
        out[(long)row * 1024 + col] = acc[i][j][r];
      }
    }
}

extern "C" void kernel_launch(void* const* d_in, const int* in_sizes, int n_in,
                              void* d_out, int out_size, void* d_ws, size_t ws_size,
                              hipStream_t stream) {
  const float* x = (const float*)d_in[0];       // [4,2048,1024]
  const float* w_qkv = (const float*)d_in[1];   // [1024,3072]
  const float* w_o = (const float*)d_in[2];     // [1024,1024]
  float* out = (float*)d_out;                   // [4,2048,1024]
  short* ws = (short*)d_ws;
  short* xb = ws;                       // bf16 x; later reused as concat
  short* wqkvT = xb + 8388608;          // [3072][1024]
  short* woT = wqkvT + 3145728;         // [1024][1024]
  short* q = woT + 1048576;             // [B,H,T,dh], pre-scaled 1/32
  short* kb = q + 8388608;              // [B,H,T,dh]
  short* vt = kb + 8388608;             // [B,H,dh,T]

  prep<<<12288, 256, 0, stream>>>(x, w_qkv, w_o, xb, wqkvT, woT);
  gemm_qkv<<<dim3(64, 24), 256, 0, stream>>>(xb, wqkvT, q, kb, vt);
  attn<<<dim3(2048), 256, 0, stream>>>(q, kb, vt, xb /*concat reuses xb*/);
  gemm_out<<<dim3(64, 8), 256, 0, stream>>>(xb, woT, out);
}

// Round 7
// 244.198 us; speedup vs baseline: 1.0124x; 1.0124x over previous
//
#include <hip/hip_runtime.h>
#include <hip/hip_bf16.h>

typedef float f32x4 __attribute__((ext_vector_type(4)));
typedef short bf16x8 __attribute__((ext_vector_type(8)));
typedef short bf16x4 __attribute__((ext_vector_type(4)));

static __device__ __forceinline__ short f2bs(float f) {
  __hip_bfloat16 h = __float2bfloat16(f);
  union { __hip_bfloat16 h; short s; } u;
  u.h = h;
  return u.s;
}

// async global->LDS, 16B per lane; LDS dest = wave-uniform base + lane*16
#define GLDS(gp, lp) __builtin_amdgcn_global_load_lds( \
    (const __attribute__((address_space(1))) unsigned int*)(gp), \
    (__attribute__((address_space(3))) unsigned int*)(lp), 16, 0, 0)

#define MFMA16(a, b, c) __builtin_amdgcn_mfma_f32_16x16x32_bf16((a), (b), (c), 0, 0, 0)
#define FENCE asm volatile("" ::: "memory")

// ---------------- fused preprocessing: one launch instead of three ----------
__global__ __launch_bounds__(256) void prep(const float* __restrict__ x,
                                            const float* __restrict__ w_qkv,
                                            const float* __restrict__ w_o,
                                            short* __restrict__ xb,
                                            short* __restrict__ wqkvT,
                                            short* __restrict__ woT) {
  __shared__ float tile[32][33];
  const int bid = blockIdx.x;
  if (bid < 8192) {
    int i = bid * 256 + threadIdx.x;
    f32x4 v = ((const f32x4*)x)[i];
    bf16x4 o;
    o[0] = f2bs(v[0]); o[1] = f2bs(v[1]); o[2] = f2bs(v[2]); o[3] = f2bs(v[3]);
    ((bf16x4*)xb)[i] = o;
    return;
  }
  const float* in; short* out; int R, C, bx, by;
  if (bid < 11264) {
    int b2 = bid - 8192;                 // 3072 blocks = 96 x 32
    in = w_qkv; out = wqkvT; R = 1024; C = 3072;
    bx = (b2 % 96) * 32; by = (b2 / 96) * 32;
  } else {
    int b3 = bid - 11264;                // 1024 blocks = 32 x 32
    in = w_o; out = woT; R = 1024; C = 1024;
    bx = (b3 % 32) * 32; by = (b3 / 32) * 32;
  }
  const int tx = threadIdx.x & 31;
  const int ty = threadIdx.x >> 5;
#pragma unroll
  for (int i = 0; i < 32; i += 8)
    tile[ty + i][tx] = in[(long)(by + ty + i) * C + bx + tx];
  __syncthreads();
#pragma unroll
  for (int i = 0; i < 32; i += 8)
    out[(long)(bx + ty + i) * R + by + tx] = f2bs(tile[tx][ty + i]);
}

// ======== 2-phase 128x128 mainloop (kept for gemm_out) ========
// Round-6 swizzle: conflicts 6.29M -> 0 (verified). T2 regime-gate confirmed:
// at this 2-phase schedule timing didn't respond (critical path = stage+
// vmcnt+barrier), but the fix is the prerequisite for 8-phase schedules.
__device__ __forceinline__ void gemm_compute_tile(const short* Ac, const short* Bc,
                                                  int r0, int c0, int lr, int quad,
                                                  f32x4 acc[4][4]) {
  const int rq = (quad ^ ((lr >> 1) & 3)) * 8;   // swizzled 16B-block offset
  bf16x8 af[4], bfr[4];
#pragma unroll
  for (int i = 0; i < 4; ++i)
    af[i] = *(const bf16x8*)(Ac + (r0 + i * 16 + lr) * 32 + rq);
#pragma unroll
  for (int j = 0; j < 4; ++j)
    bfr[j] = *(const bf16x8*)(Bc + (c0 + j * 16 + lr) * 32 + rq);
#pragma unroll
  for (int i = 0; i < 4; ++i)
#pragma unroll
    for (int j = 0; j < 4; ++j)
      acc[i][j] = MFMA16(af[i], bfr[j], acc[i][j]);
}

__device__ __forceinline__ void gemm_mainloop(const short* __restrict__ A,
                                              const short* __restrict__ Bt,
                                              int K, int rowA0, int rowB0,
                                              short* As, short* Bs,  // each 2*128*32
                                              f32x4 acc[4][4]) {
  const int tid = threadIdx.x;
  const int wave = tid >> 6;
  const int lane = tid & 63;
  const int lr = lane & 15;
  const int quad = lane >> 4;
  const int swz = ((lane & 3) ^ ((lane >> 3) & 3)) * 8;
  const short* aP = A + (long)(rowA0 + wave * 32 + (lane >> 2)) * K + swz;
  const short* bP = Bt + (long)(rowB0 + wave * 32 + (lane >> 2)) * K + swz;
  const int woff = wave * 32 * 32;
  const int r0 = (wave >> 1) * 64;
  const int c0 = (wave & 1) * 64;
  const int c16K = 16 * K;
  const int BUF = 128 * 32;
  GLDS(aP, As + woff);
  GLDS(aP + c16K, As + woff + 16 * 32);
  GLDS(bP, Bs + woff);
  GLDS(bP + c16K, Bs + woff + 16 * 32);
  aP += 32; bP += 32;
  const int nIter = K >> 5;   // even
#pragma unroll 1
  for (int i = 0; i < nIter; i += 2) {
    __syncthreads();
    if (i + 1 < nIter) {
      GLDS(aP, As + BUF + woff);
      GLDS(aP + c16K, As + BUF + woff + 16 * 32);
      GLDS(bP, Bs + BUF + woff);
      GLDS(bP + c16K, Bs + BUF + woff + 16 * 32);
      aP += 32; bP += 32;
    }
    gemm_compute_tile(As, Bs, r0, c0, lr, quad, acc);
    __syncthreads();
    if (i + 2 < nIter) {
      GLDS(aP, As + woff);
      GLDS(aP + c16K, As + woff + 16 * 32);
      GLDS(bP, Bs + woff);
      GLDS(bP + c16K, Bs + woff + 16 * 32);
      aP += 32; bP += 32;
    }
    gemm_compute_tile(As + BUF, Bs + BUF, r0, c0, lr, quad, acc);
  }
}

// ---------------- GEMM1: qkv = x @ w_qkv — 8-phase 256x256 (T3+T4) ----------
// m201-style port: 512 thr = 8 waves (2M x 4N), wave tile 128x64, BK=64,
// 128 KB LDS double-buffered (A 2x[128][64-half], B same). Per K-tile:
// 4 phases, each = {ds_read subtile, 2x GLDS for tile t+1, BAR, MFMA one
// 64x32 C-quadrant over K=64 (16 MFMA), BAR}. vmcnt(2) ONCE per K-tile at
// the boundary (2 newest = t+1's first pair stay in flight) — never 0 in
// the main loop. LDS swizzle: block b' = b ^ (row&7) as an involution
// applied at the pre-swizzled global SOURCE and the ds_read (rule 21);
// consecutive 8 lanes hit 8 distinct 16B blocks -> conflict-free.
// Per-FLOP LDS reads drop 33% vs 64x64 wave tiles -> LDS-bound ceiling
// ~1650 TF (matches m201's measured 1563-1728).
__global__ __launch_bounds__(512, 2) void gemm_qkv(const short* __restrict__ xb,
                                                   const short* __restrict__ wT,
                                                   short* __restrict__ q,
                                                   short* __restrict__ k,
                                                   short* __restrict__ vt) {
  __shared__ __align__(16) char L[131072];
  const int K = 1024;
  const int NT = 16;                    // K / 64
  const int tileM = blockIdx.x * 256;
  const int tileN = blockIdx.y * 256;
  const int tid = threadIdx.x;
  const int w = tid >> 6, l = tid & 63;
  const int lr = l & 15, quad = l >> 4;
  const int wr = w >> 2, wc = w & 3;
  // staging lane constants: GLDS g covers 8 rows; lane -> row l>>3, block l&7
  // source column-block pre-swizzled: scb = (l&7) ^ (l>>3)  (involution)
  const int sr = l >> 3;
  const int scb = (l & 7) ^ sr;
  const short* aS = xb + (long)(tileM + w * 16 + sr) * K + scb * 8;
  const short* bS = wT + (long)(tileN + w * 16 + sr) * K + scb * 8;
  const int aD = w * 2048 + l * 16;             // LDS byte offset (A region)
  const int bD = 32768 + w * 2048 + l * 16;     // B region starts at 32 KB
  // ds-read constants: frag block = ks*4+quad, swizzled ^= (row&7) = (lr&7)
  const int swz0 = (quad ^ (lr & 7)) * 16;
  const int swz1 = ((4 + quad) ^ (lr & 7)) * 16;
  const int aR = wr * 16384 + lr * 128;
  const int bR = 32768 + (wc >> 1) * 16384 + ((wc & 1) * 64 + lr) * 128;
  const long h128K = (long)128 * K;

  f32x4 acc[8][4];
#pragma unroll
  for (int i = 0; i < 8; ++i)
#pragma unroll
    for (int j = 0; j < 4; ++j)
      acc[i][j] = (f32x4){0.f, 0.f, 0.f, 0.f};
  bf16x8 aF[4][2], bF[2][2];

#define STG(src, dst) GLDS((src), (short*)(L + (dst)))
  // prologue: stage K-tile 0 into buf0 (8 GLDS)
#pragma unroll
  for (int h = 0; h < 2; ++h) {
    STG(aS + h * h128K,         h * 16384 + aD);
    STG(aS + h * h128K + 8 * K, h * 16384 + aD + 1024);
    STG(bS + h * h128K,         h * 16384 + bD);
    STG(bS + h * h128K + 8 * K, h * 16384 + bD + 1024);
  }

#pragma unroll 1
  for (int kt = 0; kt < NT; ++kt) {
    const int db = (kt & 1) << 16;      // current buffer base
    const int sb = db ^ 65536;          // staging (next) buffer base
    const bool nxt = (kt + 1 < NT);
    const long kOff = (long)(kt + 1) * 64;
    // ---- K-tile boundary: stage t+1 A-half0, counted wait, barrier
    if (nxt) {
      STG(aS + kOff,         sb + aD);
      STG(aS + 8 * K + kOff, sb + aD + 1024);
      asm volatile("s_waitcnt vmcnt(2)" ::: "memory");
    } else {
      asm volatile("s_waitcnt vmcnt(0)" ::: "memory");
    }
    __builtin_amdgcn_s_barrier();
    FENCE;
    // ---- ph0: read A(m0-3)+B(n0-1); stage t+1 A-half1; MFMA quadrant (0,0)
#pragma unroll
    for (int mi = 0; mi < 4; ++mi) {
      aF[mi][0] = *(const bf16x8*)(L + db + aR + mi * 2048 + swz0);
      aF[mi][1] = *(const bf16x8*)(L + db + aR + mi * 2048 + swz1);
    }
#pragma unroll
    for (int ni = 0; ni < 2; ++ni) {
      bF[ni][0] = *(const bf16x8*)(L + db + bR + ni * 2048 + swz0);
      bF[ni][1] = *(const bf16x8*)(L + db + bR + ni * 2048 + swz1);
    }
    if (nxt) {
      STG(aS + h128K + kOff,               sb + 16384 + aD);
      STG(aS + h128K + 8 * K + kOff,       sb + 16384 + aD + 1024);
    }
    FENCE;
    __builtin_amdgcn_s_barrier();
    FENCE;
    __builtin_amdgcn_s_setprio(1);
#pragma unroll
    for (int mi = 0; mi < 4; ++mi)
#pragma unroll
      for (int ni = 0; ni < 2; ++ni) {
        acc[mi][ni] = MFMA16(aF[mi][0], bF[ni][0], acc[mi][ni]);
        acc[mi][ni] = MFMA16(aF[mi][1], bF[ni][1], acc[mi][ni]);
      }
    __builtin_amdgcn_s_setprio(0);
    FENCE;
    __builtin_amdgcn_s_barrier();
    FENCE;
    // ---- ph1: read B(n2-3); stage t+1 B-half0; MFMA quadrant (0,1)
#pragma unroll
    for (int ni = 0; ni < 2; ++ni) {
      bF[ni][0] = *(const bf16x8*)(L + db + bR + (2 + ni) * 2048 + swz0);
      bF[ni][1] = *(const bf16x8*)(L + db + bR + (2 + ni) * 2048 + swz1);
    }
    if (nxt) {
      STG(bS + kOff,         sb + bD);
      STG(bS + 8 * K + kOff, sb + bD + 1024);
    }
    FENCE;
    __builtin_amdgcn_s_barrier();
    FENCE;
    __builtin_amdgcn_s_setprio(1);
#pragma unroll
    for (int mi = 0; mi < 4; ++mi)
#pragma unroll
      for (int ni = 0; ni < 2; ++ni) {
        acc[mi][2 + ni] = MFMA16(aF[mi][0], bF[ni][0], acc[mi][2 + ni]);
        acc[mi][2 + ni] = MFMA16(aF[mi][1], bF[ni][1], acc[mi][2 + ni]);
      }
    __builtin_amdgcn_s_setprio(0);
    FENCE;
    __builtin_amdgcn_s_barrier();
    FENCE;
    // ---- ph2: read A(m4-7); stage t+1 B-half1; MFMA quadrant (1,1)
#pragma unroll
    for (int mi = 0; mi < 4; ++mi) {
      aF[mi][0] = *(const bf16x8*)(L + db + aR + (4 + mi) * 2048 + swz0);
      aF[mi][1] = *(const bf16x8*)(L + db + aR + (4 + mi) * 2048 + swz1);
    }
    if (nxt) {
      STG(bS + h128K + kOff,         sb + 16384 + bD);
      STG(bS + h128K + 8 * K + kOff, sb + 16384 + bD + 1024);
    }
    FENCE;
    __builtin_amdgcn_s_barrier();
    FENCE;
    __builtin_amdgcn_s_setprio(1);
#pragma unroll
    for (int mi = 0; mi < 4; ++mi)
#pragma unroll
      for (int ni = 0; ni < 2; ++ni) {
        acc[4 + mi][2 + ni] = MFMA16(aF[mi][0], bF[ni][0], acc[4 + mi][2 + ni]);
        acc[4 + mi][2 + ni] = MFMA16(aF[mi][1], bF[ni][1], acc[4 + mi][2 + ni]);
      }
    __builtin_amdgcn_s_setprio(0);
    FENCE;
    __builtin_amdgcn_s_barrier();
    FENCE;
    // ---- ph3: re-read B(n0-1); MFMA quadrant (1,0)
#pragma unroll
    for (int ni = 0; ni < 2; ++ni) {
      bF[ni][0] = *(const bf16x8*)(L + db + bR + ni * 2048 + swz0);
      bF[ni][1] = *(const bf16x8*)(L + db + bR + ni * 2048 + swz1);
    }
    FENCE;
    __builtin_amdgcn_s_barrier();
    FENCE;
    __builtin_amdgcn_s_setprio(1);
#pragma unroll
    for (int mi = 0; mi < 4; ++mi)
#pragma unroll
      for (int ni = 0; ni < 2; ++ni) {
        acc[4 + mi][ni] = MFMA16(aF[mi][0], bF[ni][0], acc[4 + mi][ni]);
        acc[4 + mi][ni] = MFMA16(aF[mi][1], bF[ni][1], acc[4 + mi][ni]);
      }
    __builtin_amdgcn_s_setprio(0);
    FENCE;
    __builtin_amdgcn_s_barrier();
    FENCE;
  }
#undef STG
  // epilogue: scatter into q/k/v^T (same layout math as before, 8x4 tiles)
#pragma unroll
  for (int mt = 0; mt < 8; ++mt) {
    const int row0 = tileM + wr * 128 + mt * 16 + quad * 4;  // 4 consecutive rows
    const int b = row0 >> 11;
    const int t = row0 & 2047;
#pragma unroll
    for (int nt = 0; nt < 4; ++nt) {
      int col = tileN + wc * 64 + nt * 16 + lr;
      int region = col >> 10;    // 0=q 1=k 2=v (uniform per nt: 16 | 1024)
      int ww = col & 1023;
      int h = ww >> 6;
      int d = ww & 63;
      long bh = (long)b * 16 + h;
      if (region == 0) {
#pragma unroll
        for (int r = 0; r < 4; ++r)
          q[(bh * 2048 + t + r) * 64 + d] = f2bs(acc[mt][nt][r] * 0.03125f);  // fold 1/sqrt(C)
      } else if (region == 1) {
#pragma unroll
        for (int r = 0; r < 4; ++r)
          k[(bh * 2048 + t + r) * 64 + d] = f2bs(acc[mt][nt][r]);
      } else {
        bf16x4 pk;
#pragma unroll
        for (int r = 0; r < 4; ++r) pk[r] = f2bs(acc[mt][nt][r]);
        *(bf16x4*)(vt + (bh * 64 + d) * 2048 + t) = pk;
      }
    }
  }
}

// ---------------- flash attention with ALiBi + causal ----------------
// (unchanged from round 5: h-mix remap, fixed-max softmax, setprio kept;
// ones-MFMA l-sum quarantined per round-4 WRITE_SIZE regression)
__global__ __launch_bounds__(256, 5) void attn(const short* __restrict__ q,
                                               const short* __restrict__ kk,
                                               const short* __restrict__ vt,
                                               short* __restrict__ cat) {
  __shared__ __align__(16) short Ks[64 * 72];       // [kpos][dh], pad 72
  __shared__ __align__(16) short Vs[64 * 72];       // [d][kpos], pad 72
  __shared__ __align__(16) short Ps[4 * 16 * 72];   // per-wave P [m=16][k=64+pad]
  const int bx = blockIdx.x;                        // 0..2047
  const int g = bx >> 8;                            // residency round 0..7
  const int hshift = ((g & 1) << 3) | ((g & 2) << 1) | ((g & 4) >> 1);
  const int j = 31 - (bx >> 6);                     // q-tile index (64 rows)
  const int bh = (bx + hshift) & 63;                // h-mixed across CUs
  const int h = bh & 15;
  const int b = bh >> 4;
  const int tid = threadIdx.x;
  const int wave = tid >> 6;
  const int lane = tid & 63;
  const int lr = lane & 15;
  const int quad = lane >> 4;
  const float l2e = 1.44269504f;
  const float slope = exp2f(-0.5f * (float)(h + 1));   // 2^(-(h+1)/2)
  const float slope_l2e = slope * l2e;
  const float c2 = -2.0f * l2e;                        // fixed max = 2.0
  const int d_cut = (int)ceilf(20.0f * exp2f(0.5f * (float)(h + 1)));
  const short* kbg = kk + (long)bh * 2048 * 64;
  const short* vbg = vt + (long)bh * 64 * 2048;
  const int srow = tid >> 3;          // 0..31
  const int scol = (tid & 7) * 8;     // 0..56
  short* pw = Ps + wave * 16 * 72;

  const int q0 = j * 64;
  const int mrow0 = q0 + wave * 16;           // this wave's 16 q-rows (m = lr)
  const int kt_start = max(0, (q0 - d_cut) >> 6);
  const short* qptr = q + ((long)bh * 2048 + mrow0) * 64;
  bf16x8 qf0 = *(const bf16x8*)(qptr + (long)lr * 64 + quad * 8);
  bf16x8 qf1 = *(const bf16x8*)(qptr + (long)lr * 64 + 32 + quad * 8);
  float lp = 0.f;                             // per-lane partial row-sum (m=lr)
  f32x4 O[4];
#pragma unroll
  for (int dt = 0; dt < 4; ++dt) O[dt] = (f32x4){0.f, 0.f, 0.f, 0.f};
  float bias[4][4];
  unsigned okbits = 0;                        // diag-tile causal mask (dist<=0)
#pragma unroll
  for (int ct = 0; ct < 4; ++ct)
#pragma unroll
    for (int r = 0; r < 4; ++r) {
      int off = ct * 16 + quad * 4 + r;
      bias[ct][r] = slope_l2e * (float)(kt_start * 64 + off - mrow0 - lr) + c2;
      if (off - wave * 16 - lr <= 0) okbits |= 1u << (ct * 4 + r);
    }
  const float bstep = slope_l2e * 64.0f;

  const short* kg = kbg + (long)kt_start * 64 * 64;
  const short* vg = vbg + kt_start * 64;
  bf16x8 pk0 = *(const bf16x8*)(kg + srow * 64 + scol);
  bf16x8 pk1 = *(const bf16x8*)(kg + (srow + 32) * 64 + scol);
  bf16x8 pv0 = *(const bf16x8*)(vg + (long)srow * 2048 + scol);
  bf16x8 pv1 = *(const bf16x8*)(vg + (long)(srow + 32) * 2048 + scol);
  for (int kt = kt_start; kt <= j; ++kt) {
    *(bf16x8*)(Ks + srow * 72 + scol) = pk0;
    *(bf16x8*)(Ks + (srow + 32) * 72 + scol) = pk1;
    *(bf16x8*)(Vs + srow * 72 + scol) = pv0;
    *(bf16x8*)(Vs + (srow + 32) * 72 + scol) = pv1;
    __syncthreads();  // LDS tile ready
    if (kt < j) {     // issue next tile's loads; latency overlaps compute
      const short* kg2 = kbg + (long)(kt + 1) * 64 * 64;
      const short* vg2 = vbg + (kt + 1) * 64;
      pk0 = *(const bf16x8*)(kg2 + srow * 64 + scol);
      pk1 = *(const bf16x8*)(kg2 + (srow + 32) * 64 + scol);
      pv0 = *(const bf16x8*)(vg2 + (long)srow * 2048 + scol);
      pv1 = *(const bf16x8*)(vg2 + (long)(srow + 32) * 2048 + scol);
    }
    // S^T = K Q^T: lane holds S^T[k = kbase+ct*16+quad*4+r][m = mrow0+lr]
    f32x4 S[4];
    __builtin_amdgcn_s_setprio(1);
#pragma unroll
    for (int ct = 0; ct < 4; ++ct) {
      bf16x8 kf0 = *(const bf16x8*)(Ks + (ct * 16 + lr) * 72 + quad * 8);
      bf16x8 kf1 = *(const bf16x8*)(Ks + (ct * 16 + lr) * 72 + 32 + quad * 8);
      f32x4 a = (f32x4){0.f, 0.f, 0.f, 0.f};
      a = MFMA16(kf0, qf0, a);
      a = MFMA16(kf1, qf1, a);
      S[ct] = a;
    }
    __builtin_amdgcn_s_setprio(0);
    // fixed-max softmax: p = exp2(S*l2e + bias)
    const bool diag = (kt == j);
#pragma unroll
    for (int ct = 0; ct < 4; ++ct) {
      bf16x4 pkt;
#pragma unroll
      for (int r = 0; r < 4; ++r) {
        float arg = fmaf(S[ct][r], l2e, bias[ct][r]);
        if (diag && !(okbits & (1u << (ct * 4 + r)))) arg = -10000.0f;  // causal
        float p = exp2f(arg);
        lp += p;
        pkt[r] = f2bs(p);
        bias[ct][r] += bstep;
      }
      *(bf16x4*)(pw + lr * 72 + ct * 16 + quad * 4) = pkt;
    }
    asm volatile("s_waitcnt lgkmcnt(0)" ::: "memory");  // wave-private scratch
    bf16x8 pf0 = *(const bf16x8*)(pw + lr * 72 + quad * 8);
    bf16x8 pf1 = *(const bf16x8*)(pw + lr * 72 + 32 + quad * 8);
    __builtin_amdgcn_s_setprio(1);
#pragma unroll
    for (int dt = 0; dt < 4; ++dt) {
      bf16x8 vf0 = *(const bf16x8*)(Vs + (dt * 16 + lr) * 72 + quad * 8);
      bf16x8 vf1 = *(const bf16x8*)(Vs + (dt * 16 + lr) * 72 + 32 + quad * 8);
      O[dt] = MFMA16(pf0, vf0, O[dt]);
      O[dt] = MFMA16(pf1, vf1, O[dt]);
    }
    __builtin_amdgcn_s_setprio(0);
    __syncthreads();  // all waves done with Ks/Vs before next commit
  }
  lp += __shfl_xor(lp, 16);
  lp += __shfl_xor(lp, 32);   // now every lane holds full l for row m = lr
#pragma unroll
  for (int r = 0; r < 4; ++r) {
    float lm = __shfl(lp, quad * 4 + r);
    float inv = 1.0f / lm;
    int t = mrow0 + quad * 4 + r;
#pragma unroll
    for (int dt = 0; dt < 4; ++dt)
      cat[((long)b * 2048 + t) * 1024 + h * 64 + dt * 16 + lr] =
          f2bs(O[dt][r] * inv);
  }
}

// ---------------- GEMM2: out = concat @ w_o (fp32 out) ----------------
__global__ __launch_bounds__(256, 5) void gemm_out(const short* __restrict__ cat,
                                                   const short* __restrict__ woT,
                                                   float* __restrict__ out) {
  __shared__ __align__(16) short As[2 * 128 * 32];
  __shared__ __align__(16) short Bs[2 * 128 * 32];
  f32x4 acc[4][4];
#pragma unroll
  for (int i = 0; i < 4; ++i)
#pragma unroll
    for (int j = 0; j < 4; ++j)
      acc[i][j] = (f32x4){0.f, 0.f, 0.f, 0.f};
  const int tileM = blockIdx.x * 128;
  const int tileN = blockIdx.y * 128;
  gemm_mainloop(cat, woT, 1024, tileM, tileN, As, Bs, acc);
  const int tid = threadIdx.x;
  const int wave = tid >> 6;
  const int lane = tid & 63;
  const int lr = lane & 15;
  const int quad = lane >> 4;
#pragma unroll
  for (int i = 0; i < 4; ++i)
#pragma unroll
    for (int j = 0; j < 4; ++j) {
      int col = tileN + (wave & 1) * 64 + j * 16 + lr;
#pragma unroll
      for (int r = 0; r < 4; ++r) {
        int row = tileM + (wave >> 1) * 64 + i * 16 + quad * 4 + r;
        out[(long)row * 1024 + col] = acc[i][j][r];
      }
    }
}

extern "C" void kernel_launch(void* const* d_in, const int* in_sizes, int n_in,
                              void* d_out, int out_size, void* d_ws, size_t ws_size,
                              hipStream_t stream) {
  const float* x = (const float*)d_in[0];       // [4,2048,1024]
  const float* w_qkv = (const float*)d_in[1];   // [1024,3072]
  const float* w_o = (const float*)d_in[2];     // [1024,1024]
  float* out = (float*)d_out;                   // [4,2048,1024]
  short* ws = (short*)d_ws;
  short* xb = ws;                       // bf16 x; later reused as concat
  short* wqkvT = xb + 8388608;          // [3072][1024]
  short* woT = wqkvT + 3145728;         // [1024][1024]
  short* q = woT + 1048576;             // [B,H,T,dh], pre-scaled 1/32
  short* kb = q + 8388608;              // [B,H,T,dh]
  short* vt = kb + 8388608;             // [B,H,dh,T]

  prep<<<12288, 256, 0, stream>>>(x, w_qkv, w_o, xb, wqkvT, woT);
  gemm_qkv<<<dim3(32, 12), 512, 0, stream>>>(xb, wqkvT, q, kb, vt);
  attn<<<dim3(2048), 256, 0, stream>>>(q, kb, vt, xb /*concat reuses xb*/);
  gemm_out<<<dim3(64, 8), 256, 0, stream>>>(xb, woT, out);
}